// Round 3
// baseline (249.313 us; speedup 1.0000x reference)
//
#include <hip/hip_runtime.h>

#define BN_EPS 1e-5f

typedef unsigned short u16;
typedef __attribute__((ext_vector_type(8))) short bf16x8;
typedef __attribute__((ext_vector_type(4))) float f32x4;

__device__ __forceinline__ u16 f2bf(float x) {
  union { float f; unsigned int u; } v; v.f = x;
  unsigned int r = v.u + 0x7fffu + ((v.u >> 16) & 1u);
  return (u16)(r >> 16);
}
__device__ __forceinline__ float bf2f(u16 h) {
  union { unsigned int u; float f; } v; v.u = ((unsigned int)h) << 16;
  return v.f;
}

__device__ __forceinline__ float wave_reduce_sum(float v) {
#pragma unroll
  for (int off = 1; off < 64; off <<= 1) v += __shfl_xor(v, off, 64);
  return v;
}

// async global->LDS, 16B per lane. LDS dest = wave-uniform base + lane*16.
__device__ __forceinline__ void gload_lds16(const void* g, void* l) {
  __builtin_amdgcn_global_load_lds(
      (const __attribute__((address_space(1))) void*)g,
      (__attribute__((address_space(3))) void*)l, 16, 0, 0);
}

// ---------------------------------------------------------------------------
// Kernel 1: embeddings -> fm_first (N x 576 bf16) + partial[n] (fp32), and
// (blocks >= NBE) W1 -> W1h bf16 padded to 512 rows (rows>=400 zero).
// ---------------------------------------------------------------------------
#define NBE 4096  // N/4 embed blocks
__global__ __launch_bounds__(256) void embed_prep(
    const float* __restrict__ Xi_dense, const float* __restrict__ Xv,
    const float* __restrict__ Wd, const float* __restrict__ bd,
    const float* __restrict__ tables, const int* __restrict__ Xi_cat,
    const float* __restrict__ bias_vec, const float* __restrict__ W1,
    u16* __restrict__ fm_first, float* __restrict__ partial,
    u16* __restrict__ W1h) {
  const int t = threadIdx.x;
  if (blockIdx.x >= NBE) {  // W1 conversion region: 512*576 = 72 blocks * 4096
    const int base = (blockIdx.x - NBE) * 4096;
#pragma unroll
    for (int e = 0; e < 16; ++e) {
      const int idx = base + e * 256 + t;
      const int r = idx / 576;
      const int j = idx - r * 576;
      W1h[idx] = (r < 400) ? f2bf(W1[r * 576 + j]) : (u16)0;
    }
    return;
  }
  const int lane = t & 63;
  const int n = blockIdx.x * 4 + (t >> 6);

  const float* xv = Xv + n * 36;
  float sum_all = 0.f, s_e = 0.f, q_e = 0.f;

#pragma unroll
  for (int k = 0; k < 9; ++k) {
    const int idx = lane + 64 * k;
    const int f = idx >> 4;
    const int e = idx & 15;
    float val;
    if (f < 26) {
      val = Xi_dense[n * 26 + f] * Wd[f * 16 + e] + bd[f * 16 + e];
    } else {
      const int fc = f - 26;
      const int row = Xi_cat[n * 10 + fc];
      val = tables[(size_t)fc * 200000 * 16 + (size_t)row * 16 + e];
    }
    val *= xv[f];
    fm_first[(size_t)n * 576 + idx] = f2bf(val);
    sum_all += val;
    s_e += val;
    q_e += val * val;
  }

  float s_tot = s_e;
  s_tot += __shfl_xor(s_tot, 16, 64);
  s_tot += __shfl_xor(s_tot, 32, 64);
  float q_tot = q_e;
  q_tot += __shfl_xor(q_tot, 16, 64);
  q_tot += __shfl_xor(q_tot, 32, 64);

  const float fm2 = 0.5f * (s_tot * s_tot - q_tot);  // replicated 4x per e
  const float red1 = wave_reduce_sum(sum_all);
  const float red2 = wave_reduce_sum(fm2) * 0.25f;
  if (lane == 0) partial[n] = red1 + red2 + bias_vec[n];
}

// ---------------------------------------------------------------------------
// m97-style bf16 MFMA GEMM. Y(M x <=Ncap) = A(M x K) @ W^T + bias.
// W padded to 512 rows (zeros beyond real cols) so staging is unpredicated.
// BM=128 BN=128 BK=32; 256 thr = 4 waves (2x2); 4x4 16x16x32 frags/wave.
// Staging via global_load_lds width-16 into linear LDS [row][32] bf16.
// Epilogue: bf16 store (col<Ncap) + per-block column sum/sumsq partials.
// ---------------------------------------------------------------------------
__global__ __launch_bounds__(256) void gemm_bf16(
    const u16* __restrict__ A, int lda,
    const u16* __restrict__ W, int ldw,
    const float* __restrict__ bias, int nbias,
    u16* __restrict__ Y, int ldc, int Ncap,
    float* __restrict__ pS, float* __restrict__ pQ, int K) {
  __shared__ u16 As[128 * 32];
  __shared__ u16 Bs[128 * 32];
  __shared__ float rS[2][4][2][16];
  __shared__ float rQ[2][4][2][16];

  const int t = threadIdx.x;
  const int bm = blockIdx.x * 128;
  const int bn = blockIdx.y * 128;
  const int wid = t >> 6, lane = t & 63;
  const int wr = wid >> 1, wc = wid & 1;
  const int lr = lane & 15, lk = (lane >> 4) * 8;
  const int sr = lane >> 2;       // staging row within 16-row chunk
  const int sk = (lane & 3) * 8;  // staging k offset (elements)

  f32x4 acc[4][4] = {};

  for (int kt = 0; kt < K; kt += 32) {
#pragma unroll
    for (int i = 0; i < 2; ++i) {
      const int c = wid * 2 + i;  // chunk 0..7 (16 rows / 1KB each)
      gload_lds16(&A[(size_t)(bm + c * 16 + sr) * lda + kt + sk],
                  &As[c * 512]);
      gload_lds16(&W[(size_t)(bn + c * 16 + sr) * ldw + kt + sk],
                  &Bs[c * 512]);
    }
    __syncthreads();

    bf16x8 af[4], bfv[4];
#pragma unroll
    for (int mf = 0; mf < 4; ++mf)
      af[mf] = *(const bf16x8*)&As[(wr * 64 + mf * 16 + lr) * 32 + lk];
#pragma unroll
    for (int nf = 0; nf < 4; ++nf)
      bfv[nf] = *(const bf16x8*)&Bs[(wc * 64 + nf * 16 + lr) * 32 + lk];
#pragma unroll
    for (int mf = 0; mf < 4; ++mf)
#pragma unroll
      for (int nf = 0; nf < 4; ++nf)
        acc[mf][nf] = __builtin_amdgcn_mfma_f32_16x16x32_bf16(
            af[mf], bfv[nf], acc[mf][nf], 0, 0, 0);
    __syncthreads();
  }

  // epilogue: bias, bf16 store, per-block column stats
  const int l4 = (lane >> 4) * 4;
#pragma unroll
  for (int nf = 0; nf < 4; ++nf) {
    const int col = bn + wc * 64 + nf * 16 + lr;
    const float bb = (col < nbias) ? bias[col] : 0.f;
    float s = 0.f, q = 0.f;
#pragma unroll
    for (int mf = 0; mf < 4; ++mf) {
#pragma unroll
      for (int r = 0; r < 4; ++r) {
        const int row = bm + wr * 64 + mf * 16 + l4 + r;
        const float v = acc[mf][nf][r] + bb;
        s += v;
        q += v * v;
        if (col < Ncap) Y[(size_t)row * ldc + col] = f2bf(v);
      }
    }
    s += __shfl_xor(s, 16, 64);
    s += __shfl_xor(s, 32, 64);
    q += __shfl_xor(q, 16, 64);
    q += __shfl_xor(q, 32, 64);
    if (lane < 16) {
      rS[wc][nf][wr][lr] = s;
      rQ[wc][nf][wr][lr] = q;
    }
  }
  __syncthreads();
  if (t < 128) {  // t == wc*64 + nf*16 + c
    const int wcc = t >> 6, nff = (t >> 4) & 3, c = t & 15;
    pS[(size_t)(bn + t) * gridDim.x + blockIdx.x] =
        rS[wcc][nff][0][c] + rS[wcc][nff][1][c];
    pQ[(size_t)(bn + t) * gridDim.x + blockIdx.x] =
        rQ[wcc][nff][0][c] + rQ[wcc][nff][1][c];
  }
}

// ---------------------------------------------------------------------------
// prep2: BN1 finalize (block-local into LDS) + fold into W2/b2:
//   W2p[i][j] = bf16(W2[i][j] * a1[j])  (padded to 512 x 416)
//   b2p[i]    = b2[i] + sum_j W2[i][j] * c1[j]
// grid 128 blocks x 4 rows.
// ---------------------------------------------------------------------------
__global__ __launch_bounds__(256) void prep2(
    const float* __restrict__ pS, const float* __restrict__ pQ,
    const float* __restrict__ g1, const float* __restrict__ be1,
    const float* __restrict__ W2, const float* __restrict__ b2,
    u16* __restrict__ W2p, float* __restrict__ b2p, int NBLK) {
  __shared__ float la[400], lc[400];
  const int t = threadIdx.x;
  for (int col = t; col < 400; col += 256) {
    float S = 0.f, Q = 0.f;
    for (int b = 0; b < NBLK; ++b) {
      S += pS[(size_t)col * NBLK + b];
      Q += pQ[(size_t)col * NBLK + b];
    }
    const float mu = S * (1.f / 16384.f);
    const float var = Q * (1.f / 16384.f) - mu * mu;
    const float aa = g1[col] * rsqrtf(var + BN_EPS);
    la[col] = aa;
    lc[col] = be1[col] - mu * aa;
  }
  __syncthreads();
  const int lane = t & 63;
  const int row = blockIdx.x * 4 + (t >> 6);
  if (row >= 400) {
    for (int j = lane; j < 416; j += 64) W2p[(size_t)row * 416 + j] = 0;
    if (lane == 0) b2p[row] = 0.f;
    return;
  }
  float dot = 0.f;
  for (int j = lane; j < 416; j += 64) {
    if (j < 400) {
      const float w = W2[row * 400 + j];
      W2p[(size_t)row * 416 + j] = f2bf(w * la[j]);
      dot += w * lc[j];
    } else {
      W2p[(size_t)row * 416 + j] = 0;
    }
  }
  dot = wave_reduce_sum(dot);
  if (lane == 0) b2p[row] = b2[row] + dot;
}

// ---------------------------------------------------------------------------
// final: BN2 finalize (block-local) + out[n] = partial[n] + sum_j (a2*Y2+c2)
// grid 256 blocks x 64 rows (4 waves x 16 rows).
// ---------------------------------------------------------------------------
__global__ __launch_bounds__(256) void final_fused(
    const float* __restrict__ pS, const float* __restrict__ pQ,
    const float* __restrict__ g2, const float* __restrict__ be2,
    const u16* __restrict__ Y2, const float* __restrict__ partial,
    float* __restrict__ out, int NBLK) {
  __shared__ float la[400], lc[400];
  const int t = threadIdx.x;
  for (int col = t; col < 400; col += 256) {
    float S = 0.f, Q = 0.f;
    for (int b = 0; b < NBLK; ++b) {
      S += pS[(size_t)col * NBLK + b];
      Q += pQ[(size_t)col * NBLK + b];
    }
    const float mu = S * (1.f / 16384.f);
    const float var = Q * (1.f / 16384.f) - mu * mu;
    const float aa = g2[col] * rsqrtf(var + BN_EPS);
    la[col] = aa;
    lc[col] = be2[col] - mu * aa;
  }
  __syncthreads();
  const int lane = t & 63;
  const int wid = t >> 6;
#pragma unroll 4
  for (int rr = 0; rr < 16; ++rr) {
    const int n = blockIdx.x * 64 + wid * 16 + rr;
    const u16* y = Y2 + (size_t)n * 400;
    float acc = 0.f;
    for (int j = lane; j < 400; j += 64) acc += fmaf(la[j], bf2f(y[j]), lc[j]);
    acc = wave_reduce_sum(acc);
    if (lane == 0) out[n] = partial[n] + acc;
  }
}

extern "C" void kernel_launch(void* const* d_in, const int* in_sizes, int n_in,
                              void* d_out, int out_size, void* d_ws,
                              size_t ws_size, hipStream_t stream) {
  const float* Xi_dense = (const float*)d_in[0];
  const float* Xv = (const float*)d_in[1];
  const float* Wd = (const float*)d_in[2];
  const float* bd = (const float*)d_in[3];
  const float* tables = (const float*)d_in[4];
  const float* W1 = (const float*)d_in[5];
  const float* b1 = (const float*)d_in[6];
  const float* g1 = (const float*)d_in[7];
  const float* be1 = (const float*)d_in[8];
  const float* W2 = (const float*)d_in[9];
  const float* b2 = (const float*)d_in[10];
  const float* g2 = (const float*)d_in[11];
  const float* be2 = (const float*)d_in[12];
  const float* bias_vec = (const float*)d_in[13];
  const int* Xi_cat = (const int*)d_in[14];

  constexpr int N = 16384;
  constexpr int DIN = 576;
  constexpr int H = 400;
  constexpr int KP = 416;   // H padded to K-mult-of-32 for gemm2
  constexpr int WPAD = 512; // weight rows padded for unpredicated staging
  constexpr int MB = 128;   // gemm grid.x

  u16* fm_first = (u16*)d_ws;                        // N*576
  u16* Y1h = fm_first + (size_t)N * DIN;             // N*416
  u16* Y2h = Y1h + (size_t)N * KP;                   // N*400
  u16* W1h = Y2h + (size_t)N * H;                    // 512*576
  u16* W2p = W1h + (size_t)WPAD * DIN;               // 512*416
  float* fptr = (float*)(W2p + (size_t)WPAD * KP);
  float* partial = fptr;                             // N
  float* pS = partial + N;                           // 512*128
  float* pQ = pS + WPAD * MB;                        // 512*128
  float* b2p = pQ + WPAD * MB;                       // 512

  embed_prep<<<NBE + 72, 256, 0, stream>>>(Xi_dense, Xv, Wd, bd, tables,
                                           Xi_cat, bias_vec, W1, fm_first,
                                           partial, W1h);

  dim3 gg(MB, 4);  // 4*128 = 512 cols (padded)
  gemm_bf16<<<gg, 256, 0, stream>>>(fm_first, DIN, W1h, DIN, b1, H,
                                    Y1h, KP, KP, pS, pQ, DIN);

  prep2<<<MB, 256, 0, stream>>>(pS, pQ, g1, be1, W2, b2, W2p, b2p, MB);

  gemm_bf16<<<gg, 256, 0, stream>>>(Y1h, KP, W2p, KP, b2p, H,
                                    Y2h, H, H, pS, pQ, KP);

  final_fused<<<N / 64, 256, 0, stream>>>(pS, pQ, g2, be2, Y2h, partial,
                                          (float*)d_out, MB);
}

// Round 4
// 71.126 us; speedup vs baseline: 3.5052x; 3.5052x over previous
//
#include <hip/hip_runtime.h>

#define BN_EPS 1e-5f

typedef unsigned short u16;
typedef __attribute__((ext_vector_type(8))) short bf16x8;
typedef __attribute__((ext_vector_type(4))) float f32x4;

__device__ __forceinline__ u16 f2bf(float x) {
  union { float f; unsigned int u; } v; v.f = x;
  unsigned int r = v.u + 0x7fffu + ((v.u >> 16) & 1u);
  return (u16)(r >> 16);
}
__device__ __forceinline__ float bf2f(u16 h) {
  union { unsigned int u; float f; } v; v.u = ((unsigned int)h) << 16;
  return v.f;
}

__device__ __forceinline__ float wave_reduce_sum(float v) {
#pragma unroll
  for (int off = 1; off < 64; off <<= 1) v += __shfl_xor(v, off, 64);
  return v;
}

// async global->LDS, 16B per lane. LDS dest = wave-uniform base + lane*16.
__device__ __forceinline__ void gload_lds16(const void* g, void* l) {
  __builtin_amdgcn_global_load_lds(
      (const __attribute__((address_space(1))) void*)g,
      (__attribute__((address_space(3))) void*)l, 16, 0, 0);
}

// ---------------------------------------------------------------------------
// Kernel 1: embeddings -> fm_first (N x 576 bf16) + partial[n] (fp32), and
// (blocks >= NBE) W1 -> W1h bf16 padded to 512 rows (rows>=400 zero).
// ---------------------------------------------------------------------------
#define NBE 4096  // N/4 embed blocks
__global__ __launch_bounds__(256) void embed_prep(
    const float* __restrict__ Xi_dense, const float* __restrict__ Xv,
    const float* __restrict__ Wd, const float* __restrict__ bd,
    const float* __restrict__ tables, const int* __restrict__ Xi_cat,
    const float* __restrict__ bias_vec, const float* __restrict__ W1,
    u16* __restrict__ fm_first, float* __restrict__ partial,
    u16* __restrict__ W1h) {
  const int t = threadIdx.x;
  if (blockIdx.x >= NBE) {  // W1 conversion region: 512*576 = 72 blocks * 4096
    const int base = (blockIdx.x - NBE) * 4096;
#pragma unroll
    for (int e = 0; e < 16; ++e) {
      const int idx = base + e * 256 + t;
      const int r = idx / 576;
      const int j = idx - r * 576;
      W1h[idx] = (r < 400) ? f2bf(W1[r * 576 + j]) : (u16)0;
    }
    return;
  }
  const int lane = t & 63;
  const int n = blockIdx.x * 4 + (t >> 6);

  const float* xv = Xv + n * 36;
  float sum_all = 0.f, s_e = 0.f, q_e = 0.f;

#pragma unroll
  for (int k = 0; k < 9; ++k) {
    const int idx = lane + 64 * k;
    const int f = idx >> 4;
    const int e = idx & 15;
    float val;
    if (f < 26) {
      val = Xi_dense[n * 26 + f] * Wd[f * 16 + e] + bd[f * 16 + e];
    } else {
      const int fc = f - 26;
      const int row = Xi_cat[n * 10 + fc];
      val = tables[(size_t)fc * 200000 * 16 + (size_t)row * 16 + e];
    }
    val *= xv[f];
    fm_first[(size_t)n * 576 + idx] = f2bf(val);
    sum_all += val;
    s_e += val;
    q_e += val * val;
  }

  float s_tot = s_e;
  s_tot += __shfl_xor(s_tot, 16, 64);
  s_tot += __shfl_xor(s_tot, 32, 64);
  float q_tot = q_e;
  q_tot += __shfl_xor(q_tot, 16, 64);
  q_tot += __shfl_xor(q_tot, 32, 64);

  const float fm2 = 0.5f * (s_tot * s_tot - q_tot);  // replicated 4x per e
  const float red1 = wave_reduce_sum(sum_all);
  const float red2 = wave_reduce_sum(fm2) * 0.25f;
  if (lane == 0) partial[n] = red1 + red2 + bias_vec[n];
}

// ---------------------------------------------------------------------------
// m97-style bf16 MFMA GEMM. Y(M x <=Ncap) = A(M x K) @ W^T + bias.
// W padded to 512 rows (zeros beyond real cols) so staging is unpredicated.
// BM=128 BN=128 BK=32; 256 thr = 4 waves (2x2); 4x4 16x16x32 frags/wave.
// Staging via global_load_lds width-16 into linear LDS [row][32] bf16.
// Epilogue: bf16 store (col<Ncap) + per-block column sum/sumsq partials.
// ---------------------------------------------------------------------------
__global__ __launch_bounds__(256) void gemm_bf16(
    const u16* __restrict__ A, int lda,
    const u16* __restrict__ W, int ldw,
    const float* __restrict__ bias, int nbias,
    u16* __restrict__ Y, int ldc, int Ncap,
    float* __restrict__ pS, float* __restrict__ pQ, int K) {
  __shared__ u16 As[128 * 32];
  __shared__ u16 Bs[128 * 32];
  __shared__ float rS[2][4][2][16];
  __shared__ float rQ[2][4][2][16];

  const int t = threadIdx.x;
  const int bm = blockIdx.x * 128;
  const int bn = blockIdx.y * 128;
  const int wid = t >> 6, lane = t & 63;
  const int wr = wid >> 1, wc = wid & 1;
  const int lr = lane & 15, lk = (lane >> 4) * 8;
  const int sr = lane >> 2;       // staging row within 16-row chunk
  const int sk = (lane & 3) * 8;  // staging k offset (elements)

  f32x4 acc[4][4] = {};

  for (int kt = 0; kt < K; kt += 32) {
#pragma unroll
    for (int i = 0; i < 2; ++i) {
      const int c = wid * 2 + i;  // chunk 0..7 (16 rows / 1KB each)
      gload_lds16(&A[(size_t)(bm + c * 16 + sr) * lda + kt + sk],
                  &As[c * 512]);
      gload_lds16(&W[(size_t)(bn + c * 16 + sr) * ldw + kt + sk],
                  &Bs[c * 512]);
    }
    __syncthreads();

    bf16x8 af[4], bfv[4];
#pragma unroll
    for (int mf = 0; mf < 4; ++mf)
      af[mf] = *(const bf16x8*)&As[(wr * 64 + mf * 16 + lr) * 32 + lk];
#pragma unroll
    for (int nf = 0; nf < 4; ++nf)
      bfv[nf] = *(const bf16x8*)&Bs[(wc * 64 + nf * 16 + lr) * 32 + lk];
#pragma unroll
    for (int mf = 0; mf < 4; ++mf)
#pragma unroll
      for (int nf = 0; nf < 4; ++nf)
        acc[mf][nf] = __builtin_amdgcn_mfma_f32_16x16x32_bf16(
            af[mf], bfv[nf], acc[mf][nf], 0, 0, 0);
    __syncthreads();
  }

  // epilogue: bias, bf16 store, per-block column stats
  const int l4 = (lane >> 4) * 4;
#pragma unroll
  for (int nf = 0; nf < 4; ++nf) {
    const int col = bn + wc * 64 + nf * 16 + lr;
    const float bb = (col < nbias) ? bias[col] : 0.f;
    float s = 0.f, q = 0.f;
#pragma unroll
    for (int mf = 0; mf < 4; ++mf) {
#pragma unroll
      for (int r = 0; r < 4; ++r) {
        const int row = bm + wr * 64 + mf * 16 + l4 + r;
        const float v = acc[mf][nf][r] + bb;
        s += v;
        q += v * v;
        if (col < Ncap) Y[(size_t)row * ldc + col] = f2bf(v);
      }
    }
    s += __shfl_xor(s, 16, 64);
    s += __shfl_xor(s, 32, 64);
    q += __shfl_xor(q, 16, 64);
    q += __shfl_xor(q, 32, 64);
    if (lane < 16) {
      rS[wc][nf][wr][lr] = s;
      rQ[wc][nf][wr][lr] = q;
    }
  }
  __syncthreads();
  if (t < 128) {  // t == wc*64 + nf*16 + c
    const int wcc = t >> 6, nff = (t >> 4) & 3, c = t & 15;
    pS[(size_t)(bn + t) * gridDim.x + blockIdx.x] =
        rS[wcc][nff][0][c] + rS[wcc][nff][1][c];
    pQ[(size_t)(bn + t) * gridDim.x + blockIdx.x] =
        rQ[wcc][nff][0][c] + rQ[wcc][nff][1][c];
  }
}

// ---------------------------------------------------------------------------
// bn_ac: wave-per-column BN finalize. 100 blocks x 4 waves = 400 cols.
// Lane = partial-block index (coalesced): 4 loads + shuffles per column.
// a[col] = g*rsqrt(var+eps); c[col] = be - mu*a.
// ---------------------------------------------------------------------------
__global__ __launch_bounds__(256) void bn_ac(
    const float* __restrict__ pS, const float* __restrict__ pQ,
    const float* __restrict__ g, const float* __restrict__ be,
    float* __restrict__ a, float* __restrict__ c) {
  const int wid = threadIdx.x >> 6, lane = threadIdx.x & 63;
  const int col = blockIdx.x * 4 + wid;  // grid=100 -> col<400
  float S = pS[(size_t)col * 128 + lane] + pS[(size_t)col * 128 + 64 + lane];
  float Q = pQ[(size_t)col * 128 + lane] + pQ[(size_t)col * 128 + 64 + lane];
#pragma unroll
  for (int off = 1; off < 64; off <<= 1) {
    S += __shfl_xor(S, off, 64);
    Q += __shfl_xor(Q, off, 64);
  }
  if (lane == 0) {
    const float mu = S * (1.f / 16384.f);
    const float var = Q * (1.f / 16384.f) - mu * mu;
    const float aa = g[col] * rsqrtf(var + BN_EPS);
    a[col] = aa;
    c[col] = be[col] - mu * aa;
  }
}

// ---------------------------------------------------------------------------
// prep2: fold BN1 affine into W2/b2 (a1/c1 from global, vectorized float4):
//   W2p[i][j] = bf16(W2[i][j] * a1[j])  (padded to 512 x 416, zeros beyond)
//   b2p[i]    = b2[i] + sum_j W2[i][j] * c1[j]
// 128 blocks x 4 rows (wave per row).
// ---------------------------------------------------------------------------
__global__ __launch_bounds__(256) void prep2(
    const float* __restrict__ a1, const float* __restrict__ c1,
    const float* __restrict__ W2, const float* __restrict__ b2,
    u16* __restrict__ W2p, float* __restrict__ b2p) {
  const int t = threadIdx.x;
  const int lane = t & 63;
  const int row = blockIdx.x * 4 + (t >> 6);
  const ushort4 z4 = {0, 0, 0, 0};
  if (row >= 400) {
    const int j1 = lane * 4;
    *(ushort4*)&W2p[(size_t)row * 416 + j1] = z4;
    const int j2 = 256 + lane * 4;
    if (j2 < 416) *(ushort4*)&W2p[(size_t)row * 416 + j2] = z4;
    if (lane == 0) b2p[row] = 0.f;
    return;
  }
  float dot = 0.f;
  {  // phase 1: j = lane*4 in [0,256)
    const int j = lane * 4;
    const float4 w = *(const float4*)&W2[(size_t)row * 400 + j];
    const float4 la = *(const float4*)&a1[j];
    const float4 lc = *(const float4*)&c1[j];
    ushort4 o = {f2bf(w.x * la.x), f2bf(w.y * la.y), f2bf(w.z * la.z),
                 f2bf(w.w * la.w)};
    *(ushort4*)&W2p[(size_t)row * 416 + j] = o;
    dot += w.x * lc.x + w.y * lc.y + w.z * lc.z + w.w * lc.w;
  }
  {  // phase 2: j = 256 + lane*4 in [256,512); real cols < 400, pad < 416
    const int j = 256 + lane * 4;
    if (j < 400) {
      const float4 w = *(const float4*)&W2[(size_t)row * 400 + j];
      const float4 la = *(const float4*)&a1[j];
      const float4 lc = *(const float4*)&c1[j];
      ushort4 o = {f2bf(w.x * la.x), f2bf(w.y * la.y), f2bf(w.z * la.z),
                   f2bf(w.w * la.w)};
      *(ushort4*)&W2p[(size_t)row * 416 + j] = o;
      dot += w.x * lc.x + w.y * lc.y + w.z * lc.z + w.w * lc.w;
    } else if (j < 416) {
      *(ushort4*)&W2p[(size_t)row * 416 + j] = z4;
    }
  }
  dot = wave_reduce_sum(dot);
  if (lane == 0) b2p[row] = b2[row] + dot;
}

// ---------------------------------------------------------------------------
// final: out[n] = partial[n] + sum_j (a2[j]*Y2[n,j] + c2[j])
// 1024 blocks x 4 waves x 4 rows. Lane owns cols [lane*8, lane*8+8)
// (lanes 0..49 active); a2/c2 hoisted to registers once per wave;
// per row: one bf16x8 load + 8 fma + wave reduce.
// ---------------------------------------------------------------------------
__global__ __launch_bounds__(256) void final_kernel(
    const u16* __restrict__ Y2, const float* __restrict__ a2,
    const float* __restrict__ c2, const float* __restrict__ partial,
    float* __restrict__ out) {
  const int t = threadIdx.x;
  const int lane = t & 63;
  const int wid = t >> 6;
  const int j0 = lane * 8;
  float ar[8], cr[8];
  if (j0 < 400) {
    const float4 a0 = *(const float4*)&a2[j0];
    const float4 a1v = *(const float4*)&a2[j0 + 4];
    const float4 c0 = *(const float4*)&c2[j0];
    const float4 c1v = *(const float4*)&c2[j0 + 4];
    ar[0] = a0.x; ar[1] = a0.y; ar[2] = a0.z; ar[3] = a0.w;
    ar[4] = a1v.x; ar[5] = a1v.y; ar[6] = a1v.z; ar[7] = a1v.w;
    cr[0] = c0.x; cr[1] = c0.y; cr[2] = c0.z; cr[3] = c0.w;
    cr[4] = c1v.x; cr[5] = c1v.y; cr[6] = c1v.z; cr[7] = c1v.w;
  } else {
#pragma unroll
    for (int k = 0; k < 8; ++k) { ar[k] = 0.f; cr[k] = 0.f; }
  }
#pragma unroll
  for (int r = 0; r < 4; ++r) {
    const int n = blockIdx.x * 16 + wid * 4 + r;
    float acc = 0.f;
    if (j0 < 400) {
      const bf16x8 y = *(const bf16x8*)&Y2[(size_t)n * 400 + j0];
#pragma unroll
      for (int k = 0; k < 8; ++k)
        acc += fmaf(ar[k], bf2f((u16)y[k]), cr[k]);
    }
    acc = wave_reduce_sum(acc);
    if (lane == 0) out[n] = partial[n] + acc;
  }
}

extern "C" void kernel_launch(void* const* d_in, const int* in_sizes, int n_in,
                              void* d_out, int out_size, void* d_ws,
                              size_t ws_size, hipStream_t stream) {
  const float* Xi_dense = (const float*)d_in[0];
  const float* Xv = (const float*)d_in[1];
  const float* Wd = (const float*)d_in[2];
  const float* bd = (const float*)d_in[3];
  const float* tables = (const float*)d_in[4];
  const float* W1 = (const float*)d_in[5];
  const float* b1 = (const float*)d_in[6];
  const float* g1 = (const float*)d_in[7];
  const float* be1 = (const float*)d_in[8];
  const float* W2 = (const float*)d_in[9];
  const float* b2 = (const float*)d_in[10];
  const float* g2 = (const float*)d_in[11];
  const float* be2 = (const float*)d_in[12];
  const float* bias_vec = (const float*)d_in[13];
  const int* Xi_cat = (const int*)d_in[14];

  constexpr int N = 16384;
  constexpr int DIN = 576;
  constexpr int H = 400;
  constexpr int KP = 416;   // H padded to K-mult-of-32 for gemm2
  constexpr int WPAD = 512; // weight rows padded for unpredicated staging
  constexpr int MB = 128;   // gemm grid.x

  u16* fm_first = (u16*)d_ws;                        // N*576
  u16* Y1h = fm_first + (size_t)N * DIN;             // N*416
  u16* Y2h = Y1h + (size_t)N * KP;                   // N*400
  u16* W1h = Y2h + (size_t)N * H;                    // 512*576
  u16* W2p = W1h + (size_t)WPAD * DIN;               // 512*416
  float* fptr = (float*)(W2p + (size_t)WPAD * KP);
  float* partial = fptr;                             // N
  float* pS = partial + N;                           // 512*128
  float* pQ = pS + WPAD * MB;                        // 512*128
  float* a1 = pQ + WPAD * MB;                        // 512
  float* c1 = a1 + WPAD;
  float* a2 = c1 + WPAD;
  float* c2 = a2 + WPAD;
  float* b2p = c2 + WPAD;                            // 512

  embed_prep<<<NBE + 72, 256, 0, stream>>>(Xi_dense, Xv, Wd, bd, tables,
                                           Xi_cat, bias_vec, W1, fm_first,
                                           partial, W1h);

  dim3 gg(MB, 4);  // 4*128 = 512 cols (padded)
  gemm_bf16<<<gg, 256, 0, stream>>>(fm_first, DIN, W1h, DIN, b1, H,
                                    Y1h, KP, KP, pS, pQ, DIN);

  bn_ac<<<100, 256, 0, stream>>>(pS, pQ, g1, be1, a1, c1);
  prep2<<<MB, 256, 0, stream>>>(a1, c1, W2, b2, W2p, b2p);

  gemm_bf16<<<gg, 256, 0, stream>>>(Y1h, KP, W2p, KP, b2p, H,
                                    Y2h, H, H, pS, pQ, KP);

  bn_ac<<<100, 256, 0, stream>>>(pS, pQ, g2, be2, a2, c2);

  final_kernel<<<N / 16, 256, 0, stream>>>(Y2h, a2, c2, partial,
                                           (float*)d_out);
}

// Round 5
// 67.883 us; speedup vs baseline: 3.6727x; 1.0478x over previous
//
#include <hip/hip_runtime.h>

#define BN_EPS 1e-5f

typedef unsigned short u16;
typedef __attribute__((ext_vector_type(8))) short bf16x8;
typedef __attribute__((ext_vector_type(4))) float f32x4;

__device__ __forceinline__ u16 f2bf(float x) {
  union { float f; unsigned int u; } v; v.f = x;
  unsigned int r = v.u + 0x7fffu + ((v.u >> 16) & 1u);
  return (u16)(r >> 16);
}
__device__ __forceinline__ float bf2f(u16 h) {
  union { unsigned int u; float f; } v; v.u = ((unsigned int)h) << 16;
  return v.f;
}

__device__ __forceinline__ float wave_reduce_sum(float v) {
#pragma unroll
  for (int off = 1; off < 64; off <<= 1) v += __shfl_xor(v, off, 64);
  return v;
}

// async global->LDS, 16B per lane. LDS dest = wave-uniform base + lane*16.
__device__ __forceinline__ void gload_lds16(const void* g, void* l) {
  __builtin_amdgcn_global_load_lds(
      (const __attribute__((address_space(1))) void*)g,
      (__attribute__((address_space(3))) void*)l, 16, 0, 0);
}

// ---------------------------------------------------------------------------
// Kernel 1: embeddings -> fm_first (N x 576 bf16) + partial[n] (fp32), and
// (blocks >= NBE) W1 -> W1h bf16 padded to 512 rows (rows>=400 zero).
// ---------------------------------------------------------------------------
#define NBE 4096  // N/4 embed blocks
__global__ __launch_bounds__(256) void embed_prep(
    const float* __restrict__ Xi_dense, const float* __restrict__ Xv,
    const float* __restrict__ Wd, const float* __restrict__ bd,
    const float* __restrict__ tables, const int* __restrict__ Xi_cat,
    const float* __restrict__ bias_vec, const float* __restrict__ W1,
    u16* __restrict__ fm_first, float* __restrict__ partial,
    u16* __restrict__ W1h) {
  const int t = threadIdx.x;
  if (blockIdx.x >= NBE) {  // W1 conversion region: 512*576 = 72 blocks * 4096
    const int base = (blockIdx.x - NBE) * 4096;
#pragma unroll
    for (int e = 0; e < 16; ++e) {
      const int idx = base + e * 256 + t;
      const int r = idx / 576;
      const int j = idx - r * 576;
      W1h[idx] = (r < 400) ? f2bf(W1[r * 576 + j]) : (u16)0;
    }
    return;
  }
  const int lane = t & 63;
  const int n = blockIdx.x * 4 + (t >> 6);

  const float* xv = Xv + n * 36;
  float sum_all = 0.f, s_e = 0.f, q_e = 0.f;

#pragma unroll
  for (int k = 0; k < 9; ++k) {
    const int idx = lane + 64 * k;
    const int f = idx >> 4;
    const int e = idx & 15;
    float val;
    if (f < 26) {
      val = Xi_dense[n * 26 + f] * Wd[f * 16 + e] + bd[f * 16 + e];
    } else {
      const int fc = f - 26;
      const int row = Xi_cat[n * 10 + fc];
      val = tables[(size_t)fc * 200000 * 16 + (size_t)row * 16 + e];
    }
    val *= xv[f];
    fm_first[(size_t)n * 576 + idx] = f2bf(val);
    sum_all += val;
    s_e += val;
    q_e += val * val;
  }

  float s_tot = s_e;
  s_tot += __shfl_xor(s_tot, 16, 64);
  s_tot += __shfl_xor(s_tot, 32, 64);
  float q_tot = q_e;
  q_tot += __shfl_xor(q_tot, 16, 64);
  q_tot += __shfl_xor(q_tot, 32, 64);

  const float fm2 = 0.5f * (s_tot * s_tot - q_tot);  // replicated 4x per e
  const float red1 = wave_reduce_sum(sum_all);
  const float red2 = wave_reduce_sum(fm2) * 0.25f;
  if (lane == 0) partial[n] = red1 + red2 + bias_vec[n];
}

// ---------------------------------------------------------------------------
// bf16 MFMA GEMM body. BM=64 BN=128 BK=32, 256 thr = 4 waves (2 row x 2 col),
// 2x4 16x16x32 frags/wave. NFR=4: full 128-col tile. NFR=2: tail tile
// (only cols [bn, bn+32) meaningful; wc==1 waves idle; B-staging 2 chunks).
// ---------------------------------------------------------------------------
template <int NFR>
__device__ __forceinline__ void gemm_body(
    const u16* __restrict__ A, int lda, const u16* __restrict__ W, int ldw,
    const float* __restrict__ bias, int nbias, u16* __restrict__ Y, int ldc,
    int Ncap, float* __restrict__ pS, float* __restrict__ pQ, int K, int nxb,
    int bx, int by, u16* As, u16* Bs, float (&rS)[2][4][2][16],
    float (&rQ)[2][4][2][16]) {
  const int t = threadIdx.x;
  const int bm = bx * 64;
  const int bn = by * 128;
  const int wid = t >> 6, lane = t & 63;
  const int wr = wid >> 1, wc = wid & 1;
  const int lr = lane & 15, lk = (lane >> 4) * 8;
  const int sr = lane >> 2;       // staging row within 16-row chunk
  const int sk = (lane & 3) * 8;  // staging k offset (elements)
  const bool active = (NFR == 4) || (wc == 0);

  f32x4 acc[2][NFR] = {};

  for (int kt = 0; kt < K; kt += 32) {
    // A: 4 chunks of 16 rows; wave w stages chunk w.
    gload_lds16(&A[(size_t)(bm + wid * 16 + sr) * lda + kt + sk],
                &As[wid * 512]);
    // B: 8 chunks; wave w stages chunks 2w, 2w+1 (tail: only c<2).
#pragma unroll
    for (int i = 0; i < 2; ++i) {
      const int c = wid * 2 + i;
      if (NFR == 4 || c < 2)
        gload_lds16(&W[(size_t)(bn + c * 16 + sr) * ldw + kt + sk],
                    &Bs[c * 512]);
    }
    __syncthreads();

    if (active) {
      bf16x8 af[2], bfv[NFR];
#pragma unroll
      for (int mf = 0; mf < 2; ++mf)
        af[mf] = *(const bf16x8*)&As[(wr * 32 + mf * 16 + lr) * 32 + lk];
#pragma unroll
      for (int nf = 0; nf < NFR; ++nf)
        bfv[nf] = *(const bf16x8*)&Bs[(wc * 64 + nf * 16 + lr) * 32 + lk];
#pragma unroll
      for (int mf = 0; mf < 2; ++mf)
#pragma unroll
        for (int nf = 0; nf < NFR; ++nf)
          acc[mf][nf] = __builtin_amdgcn_mfma_f32_16x16x32_bf16(
              af[mf], bfv[nf], acc[mf][nf], 0, 0, 0);
    }
    __syncthreads();
  }

  // epilogue: bias, bf16 store, per-block column stats
  const int l4 = (lane >> 4) * 4;
  if (active) {
#pragma unroll
    for (int nf = 0; nf < NFR; ++nf) {
      const int col = bn + wc * 64 + nf * 16 + lr;
      const float bb = (col < nbias) ? bias[col] : 0.f;
      float s = 0.f, q = 0.f;
#pragma unroll
      for (int mf = 0; mf < 2; ++mf) {
#pragma unroll
        for (int r = 0; r < 4; ++r) {
          const int row = bm + wr * 32 + mf * 16 + l4 + r;
          const float v = acc[mf][nf][r] + bb;
          s += v;
          q += v * v;
          if (col < Ncap) Y[(size_t)row * ldc + col] = f2bf(v);
        }
      }
      s += __shfl_xor(s, 16, 64);
      s += __shfl_xor(s, 32, 64);
      q += __shfl_xor(q, 16, 64);
      q += __shfl_xor(q, 32, 64);
      if (lane < 16) {
        rS[wc][nf][wr][lr] = s;
        rQ[wc][nf][wr][lr] = q;
      }
    }
  }
  __syncthreads();
  if (t < (NFR == 4 ? 128 : 32)) {  // t == wc*64 + nf*16 + c
    const int wcc = t >> 6, nff = (t >> 4) & 3, c = t & 15;
    pS[(size_t)(bn + t) * nxb + bx] =
        rS[wcc][nff][0][c] + rS[wcc][nff][1][c];
    pQ[(size_t)(bn + t) * nxb + bx] =
        rQ[wcc][nff][0][c] + rQ[wcc][nff][1][c];
  }
}

// 1-D grid, y-inner ordering + XCD-chunked swizzle: the 4 y-siblings that
// share an A-panel land on the same XCD (L2 locality). nwg must be %8==0.
__global__ __launch_bounds__(256) void gemm_bf16(
    const u16* __restrict__ A, int lda,
    const u16* __restrict__ W, int ldw,
    const float* __restrict__ bias, int nbias,
    u16* __restrict__ Y, int ldc, int Ncap,
    float* __restrict__ pS, float* __restrict__ pQ, int K, int nxb) {
  __shared__ u16 As[64 * 32];
  __shared__ u16 Bs[128 * 32];
  __shared__ float rS[2][4][2][16];
  __shared__ float rQ[2][4][2][16];
  const int bid = blockIdx.x;
  const int l = (bid & 7) * (gridDim.x >> 3) + (bid >> 3);
  const int bx = l >> 2, by = l & 3;
  if (by < 3)
    gemm_body<4>(A, lda, W, ldw, bias, nbias, Y, ldc, Ncap, pS, pQ, K, nxb,
                 bx, by, As, Bs, rS, rQ);
  else
    gemm_body<2>(A, lda, W, ldw, bias, nbias, Y, ldc, Ncap, pS, pQ, K, nxb,
                 bx, by, As, Bs, rS, rQ);
}

// ---------------------------------------------------------------------------
// bn_ac: wave-per-column BN finalize. 100 blocks x 4 waves = 400 cols.
// Lane = partial-block index (coalesced): 4 loads + shuffles per column.
// ---------------------------------------------------------------------------
__global__ __launch_bounds__(256) void bn_ac(
    const float* __restrict__ pS, const float* __restrict__ pQ,
    const float* __restrict__ g, const float* __restrict__ be,
    float* __restrict__ a, float* __restrict__ c, int nxb) {
  const int wid = threadIdx.x >> 6, lane = threadIdx.x & 63;
  const int col = blockIdx.x * 4 + wid;  // grid=100 -> col<400
  float S = 0.f, Q = 0.f;
  for (int i = lane; i < nxb; i += 64) {
    S += pS[(size_t)col * nxb + i];
    Q += pQ[(size_t)col * nxb + i];
  }
#pragma unroll
  for (int off = 1; off < 64; off <<= 1) {
    S += __shfl_xor(S, off, 64);
    Q += __shfl_xor(Q, off, 64);
  }
  if (lane == 0) {
    const float mu = S * (1.f / 16384.f);
    const float var = Q * (1.f / 16384.f) - mu * mu;
    const float aa = g[col] * rsqrtf(var + BN_EPS);
    a[col] = aa;
    c[col] = be[col] - mu * aa;
  }
}

// ---------------------------------------------------------------------------
// prep2: fold BN1 affine into W2/b2 (a1/c1 from global, vectorized float4):
//   W2p[i][j] = bf16(W2[i][j] * a1[j])  (padded to 512 x 416, zeros beyond)
//   b2p[i]    = b2[i] + sum_j W2[i][j] * c1[j]
// 128 blocks x 4 rows (wave per row).
// ---------------------------------------------------------------------------
__global__ __launch_bounds__(256) void prep2(
    const float* __restrict__ a1, const float* __restrict__ c1,
    const float* __restrict__ W2, const float* __restrict__ b2,
    u16* __restrict__ W2p, float* __restrict__ b2p) {
  const int t = threadIdx.x;
  const int lane = t & 63;
  const int row = blockIdx.x * 4 + (t >> 6);
  const ushort4 z4 = {0, 0, 0, 0};
  if (row >= 400) {
    const int j1 = lane * 4;
    *(ushort4*)&W2p[(size_t)row * 416 + j1] = z4;
    const int j2 = 256 + lane * 4;
    if (j2 < 416) *(ushort4*)&W2p[(size_t)row * 416 + j2] = z4;
    if (lane == 0) b2p[row] = 0.f;
    return;
  }
  float dot = 0.f;
  {  // phase 1: j = lane*4 in [0,256)
    const int j = lane * 4;
    const float4 w = *(const float4*)&W2[(size_t)row * 400 + j];
    const float4 la = *(const float4*)&a1[j];
    const float4 lc = *(const float4*)&c1[j];
    ushort4 o = {f2bf(w.x * la.x), f2bf(w.y * la.y), f2bf(w.z * la.z),
                 f2bf(w.w * la.w)};
    *(ushort4*)&W2p[(size_t)row * 416 + j] = o;
    dot += w.x * lc.x + w.y * lc.y + w.z * lc.z + w.w * lc.w;
  }
  {  // phase 2: j = 256 + lane*4 in [256,512); real cols < 400, pad < 416
    const int j = 256 + lane * 4;
    if (j < 400) {
      const float4 w = *(const float4*)&W2[(size_t)row * 400 + j];
      const float4 la = *(const float4*)&a1[j];
      const float4 lc = *(const float4*)&c1[j];
      ushort4 o = {f2bf(w.x * la.x), f2bf(w.y * la.y), f2bf(w.z * la.z),
                   f2bf(w.w * la.w)};
      *(ushort4*)&W2p[(size_t)row * 416 + j] = o;
      dot += w.x * lc.x + w.y * lc.y + w.z * lc.z + w.w * lc.w;
    } else if (j < 416) {
      *(ushort4*)&W2p[(size_t)row * 416 + j] = z4;
    }
  }
  dot = wave_reduce_sum(dot);
  if (lane == 0) b2p[row] = b2[row] + dot;
}

// ---------------------------------------------------------------------------
// final: out[n] = partial[n] + sum_j (a2[j]*Y2[n,j] + c2[j])
// 1024 blocks x 4 waves x 4 rows. Lane owns cols [lane*8, lane*8+8).
// ---------------------------------------------------------------------------
__global__ __launch_bounds__(256) void final_kernel(
    const u16* __restrict__ Y2, const float* __restrict__ a2,
    const float* __restrict__ c2, const float* __restrict__ partial,
    float* __restrict__ out) {
  const int t = threadIdx.x;
  const int lane = t & 63;
  const int wid = t >> 6;
  const int j0 = lane * 8;
  float ar[8], cr[8];
  if (j0 < 400) {
    const float4 a0 = *(const float4*)&a2[j0];
    const float4 a1v = *(const float4*)&a2[j0 + 4];
    const float4 c0 = *(const float4*)&c2[j0];
    const float4 c1v = *(const float4*)&c2[j0 + 4];
    ar[0] = a0.x; ar[1] = a0.y; ar[2] = a0.z; ar[3] = a0.w;
    ar[4] = a1v.x; ar[5] = a1v.y; ar[6] = a1v.z; ar[7] = a1v.w;
    cr[0] = c0.x; cr[1] = c0.y; cr[2] = c0.z; cr[3] = c0.w;
    cr[4] = c1v.x; cr[5] = c1v.y; cr[6] = c1v.z; cr[7] = c1v.w;
  } else {
#pragma unroll
    for (int k = 0; k < 8; ++k) { ar[k] = 0.f; cr[k] = 0.f; }
  }
#pragma unroll
  for (int r = 0; r < 4; ++r) {
    const int n = blockIdx.x * 16 + wid * 4 + r;
    float acc = 0.f;
    if (j0 < 400) {
      const bf16x8 y = *(const bf16x8*)&Y2[(size_t)n * 400 + j0];
#pragma unroll
      for (int k = 0; k < 8; ++k)
        acc += fmaf(ar[k], bf2f((u16)y[k]), cr[k]);
    }
    acc = wave_reduce_sum(acc);
    if (lane == 0) out[n] = partial[n] + acc;
  }
}

extern "C" void kernel_launch(void* const* d_in, const int* in_sizes, int n_in,
                              void* d_out, int out_size, void* d_ws,
                              size_t ws_size, hipStream_t stream) {
  const float* Xi_dense = (const float*)d_in[0];
  const float* Xv = (const float*)d_in[1];
  const float* Wd = (const float*)d_in[2];
  const float* bd = (const float*)d_in[3];
  const float* tables = (const float*)d_in[4];
  const float* W1 = (const float*)d_in[5];
  const float* b1 = (const float*)d_in[6];
  const float* g1 = (const float*)d_in[7];
  const float* be1 = (const float*)d_in[8];
  const float* W2 = (const float*)d_in[9];
  const float* b2 = (const float*)d_in[10];
  const float* g2 = (const float*)d_in[11];
  const float* be2 = (const float*)d_in[12];
  const float* bias_vec = (const float*)d_in[13];
  const int* Xi_cat = (const int*)d_in[14];

  constexpr int N = 16384;
  constexpr int DIN = 576;
  constexpr int H = 400;
  constexpr int KP = 416;   // H padded to K-mult-of-32 for gemm2
  constexpr int WPAD = 512; // weight rows padded for unpredicated staging
  constexpr int NXB = 256;  // gemm x-blocks (N/64)

  u16* fm_first = (u16*)d_ws;                        // N*576
  u16* Y1h = fm_first + (size_t)N * DIN;             // N*416
  u16* Y2h = Y1h + (size_t)N * KP;                   // N*400
  u16* W1h = Y2h + (size_t)N * H;                    // 512*576
  u16* W2p = W1h + (size_t)WPAD * DIN;               // 512*416
  float* fptr = (float*)(W2p + (size_t)WPAD * KP);
  float* partial = fptr;                             // N
  float* pS = partial + N;                           // 512*256
  float* pQ = pS + WPAD * NXB;                       // 512*256
  float* a1 = pQ + WPAD * NXB;                       // 512
  float* c1 = a1 + WPAD;
  float* a2 = c1 + WPAD;
  float* c2 = a2 + WPAD;
  float* b2p = c2 + WPAD;                            // 512

  embed_prep<<<NBE + 72, 256, 0, stream>>>(Xi_dense, Xv, Wd, bd, tables,
                                           Xi_cat, bias_vec, W1, fm_first,
                                           partial, W1h);

  gemm_bf16<<<NXB * 4, 256, 0, stream>>>(fm_first, DIN, W1h, DIN, b1, H,
                                         Y1h, KP, KP, pS, pQ, DIN, NXB);

  bn_ac<<<100, 256, 0, stream>>>(pS, pQ, g1, be1, a1, c1, NXB);
  prep2<<<128, 256, 0, stream>>>(a1, c1, W2, b2, W2p, b2p);

  gemm_bf16<<<NXB * 4, 256, 0, stream>>>(Y1h, KP, W2p, KP, b2p, H,
                                         Y2h, H, H, pS, pQ, KP, NXB);

  bn_ac<<<100, 256, 0, stream>>>(pS, pQ, g2, be2, a2, c2, NXB);

  final_kernel<<<N / 16, 256, 0, stream>>>(Y2h, a2, c2, partial,
                                           (float*)d_out);
}